// Round 1
// baseline (353.910 us; speedup 1.0000x reference)
//
#include <hip/hip_runtime.h>

// Problem constants: V=100000, H=128, B=1024, L=512
#define V_TOK 100000
#define GAT_H 128
#define GAT_L 512
#define GAT_B 1024
#define CHUNK 8   // consecutive positions per wave; loads CHUNK+1 rows instead of 2*CHUNK

typedef float v2f __attribute__((ext_vector_type(2)));

// ---- kernel 0: S1 = sum(a1), S2 = sum(a2) -> sbuf[0..1] (one wave) ----
__global__ void k_sums(const float* __restrict__ a, float* __restrict__ sbuf) {
    const int lane = threadIdx.x & 63;
    const float2 a1 = ((const float2*)a)[lane];
    const float2 a2 = ((const float2*)(a + GAT_H))[lane];
    float s1 = a1.x + a1.y, s2 = a2.x + a2.y;
    #pragma unroll
    for (int m = 32; m >= 1; m >>= 1) {
        s1 += __shfl_xor(s1, m, 64);
        s2 += __shfl_xor(s2, m, 64);
    }
    if (lane == 0) { sbuf[0] = s1; sbuf[1] = s2; }
}

// ---- kernel 1: per-token dots t1[v]=emb[v].a1, t2[v]=emb[v].a2 ----
// Regular (caching) loads on emb: this pass warms L3 with the full table.
__global__ __launch_bounds__(256) void k_tok(const float* __restrict__ emb,
                                             const float* __restrict__ a,
                                             float* __restrict__ t1,
                                             float* __restrict__ t2) {
    const int wid = (blockIdx.x * blockDim.x + threadIdx.x) >> 6;
    const int lane = threadIdx.x & 63;
    if (wid >= V_TOK) return;
    const float2 e  = ((const float2*)(emb + (size_t)wid * GAT_H))[lane];
    const float2 a1 = ((const float2*)a)[lane];
    const float2 a2 = ((const float2*)(a + GAT_H))[lane];
    float d1 = e.x * a1.x + e.y * a1.y;
    float d2 = e.x * a2.x + e.y * a2.y;
    #pragma unroll
    for (int m = 32; m >= 1; m >>= 1) {
        d1 += __shfl_xor(d1, m, 64);
        d2 += __shfl_xor(d2, m, 64);
    }
    if (lane == 0) { t1[wid] = d1; t2[wid] = d2; }
}

// ---- kernel 2: main. One wave per CHUNK consecutive positions of one b. ----
// Scores come from token-dot tables (no reductions); each emb row loaded once
// per chunk (streamed, reused as both x_l and x_{l+1}).
// Output stores are NON-TEMPORAL: out is write-once (268 MB/iter) and would
// otherwise evict the 51 MB emb table from the memory-side L3, turning the
// ~300 MB of gather re-reads into HBM misses.
__global__ __launch_bounds__(256) void k_main(const float* __restrict__ emb,
                                              const int* __restrict__ seq,
                                              const int* __restrict__ seq_l,
                                              const float* __restrict__ t1,
                                              const float* __restrict__ t2,
                                              const float* __restrict__ sbuf,
                                              float* __restrict__ out) {
    const int wid  = (blockIdx.x * blockDim.x + threadIdx.x) >> 6;
    const int lane = threadIdx.x & 63;
    const int n_chunks = GAT_L / CHUNK;
    const int b  = wid / n_chunks;
    const int l0 = (wid - b * n_chunks) * CHUNK;
    if (b >= GAT_B) return;

    const int sl = __builtin_amdgcn_readfirstlane(seq_l[b]);
    const float S1 = sbuf[0], S2 = sbuf[1];

    int tok = __builtin_amdgcn_readfirstlane(seq[b * GAT_L + l0]);
    float2 R = ((const float2*)(emb + (size_t)tok * GAT_H))[lane];
    float t1c = t1[tok], t2c = t2[tok];
    float2* obase = (float2*)(out + ((size_t)b * GAT_L + l0) * GAT_H);

    #pragma unroll
    for (int k = 0; k < CHUNK; ++k) {
        const int l = l0 + k;
        const bool valid = (l < sl - 1);            // wave-uniform
        const bool need_next = valid || (k < CHUNK - 1);
        float2 Rn; float t1n = 0.f, t2n = 0.f;
        if (need_next) {
            // valid => l+1 <= sl-1 <= 510 < L; k<CHUNK-1 => l+1 within chunk
            const int tokn = __builtin_amdgcn_readfirstlane(seq[b * GAT_L + l + 1]);
            Rn  = ((const float2*)(emb + (size_t)tokn * GAT_H))[lane];
            t1n = t1[tokn]; t2n = t2[tokn];
        }
        v2f o2;
        if (valid) {
            const float pos  = (float)(sl - l);
            const float posn = pos - 1.0f;
            const float d1  = t1c + pos * S1;
            const float d2  = t2c + pos * S2;
            const float d2n = t2n + posn * S2;     // = next position's self-a2 dot
            const float s0 = d1 + d2, s1 = d1 + d2n;
            const float mx = fmaxf(s0, s1);
            const float p0 = __expf(s0 - mx), p1 = __expf(s1 - mx);
            const float inv = 1.0f / (p0 + p1);
            const float att0 = p0 * inv, att1 = p1 * inv;
            o2.x = att0 * (R.x + pos) + att1 * (Rn.x + posn);
            o2.y = att0 * (R.y + pos) + att1 * (Rn.y + posn);
        } else {
            o2.x = R.x;                             // out = raw embedding
            o2.y = R.y;
        }
        __builtin_nontemporal_store(o2, (v2f*)(obase + (size_t)k * 64 + lane));
        if (need_next) { R = Rn; t1c = t1n; t2c = t2n; }
    }
}

extern "C" void kernel_launch(void* const* d_in, const int* in_sizes, int n_in,
                              void* d_out, int out_size, void* d_ws, size_t ws_size,
                              hipStream_t stream) {
    const float* emb   = (const float*)d_in[0];
    const float* a     = (const float*)d_in[1];
    const int*   seq   = (const int*)d_in[2];
    const int*   seq_l = (const int*)d_in[3];
    float* out = (float*)d_out;

    float* t1   = (float*)d_ws;             // V floats
    float* t2   = t1 + V_TOK;               // V floats
    float* sbuf = t2 + V_TOK;               // 2 floats

    k_sums<<<1, 64, 0, stream>>>(a, sbuf);

    {   // per-token dots: one wave per token
        const int waves = V_TOK;
        const int blocks = (waves * 64 + 255) / 256;
        k_tok<<<blocks, 256, 0, stream>>>(emb, a, t1, t2);
    }

    {   // main: B * (L/CHUNK) waves
        const int waves = GAT_B * (GAT_L / CHUNK);
        const int blocks = (waves * 64 + 255) / 256;
        k_main<<<blocks, 256, 0, stream>>>(emb, seq, seq_l, t1, t2, sbuf, out);
    }
}

// Round 2
// 343.590 us; speedup vs baseline: 1.0300x; 1.0300x over previous
//
#include <hip/hip_runtime.h>

// Problem constants: V=100000, H=128, B=1024, L=512
#define V_TOK 100000
#define GAT_H 128
#define GAT_L 512
#define GAT_B 1024
#define CHUNK 8   // consecutive positions per wave; loads CHUNK+1 rows instead of 2*CHUNK

typedef float v2f __attribute__((ext_vector_type(2)));

__device__ __forceinline__ float readlane_f(float v, int l) {
    return __int_as_float(__builtin_amdgcn_readlane(__float_as_int(v), l));
}

// ---- kernel 0: S1 = sum(a1), S2 = sum(a2) -> sbuf[0..1] (one wave) ----
__global__ void k_sums(const float* __restrict__ a, float* __restrict__ sbuf) {
    const int lane = threadIdx.x & 63;
    const float2 a1 = ((const float2*)a)[lane];
    const float2 a2 = ((const float2*)(a + GAT_H))[lane];
    float s1 = a1.x + a1.y, s2 = a2.x + a2.y;
    #pragma unroll
    for (int m = 32; m >= 1; m >>= 1) {
        s1 += __shfl_xor(s1, m, 64);
        s2 += __shfl_xor(s2, m, 64);
    }
    if (lane == 0) { sbuf[0] = s1; sbuf[1] = s2; }
}

// ---- kernel 1: per-token dots t1[v]=emb[v].a1, t2[v]=emb[v].a2 ----
__global__ __launch_bounds__(256) void k_tok(const float* __restrict__ emb,
                                             const float* __restrict__ a,
                                             float* __restrict__ t1,
                                             float* __restrict__ t2) {
    const int wid = (blockIdx.x * blockDim.x + threadIdx.x) >> 6;
    const int lane = threadIdx.x & 63;
    if (wid >= V_TOK) return;
    const float2 e  = ((const float2*)(emb + (size_t)wid * GAT_H))[lane];
    const float2 a1 = ((const float2*)a)[lane];
    const float2 a2 = ((const float2*)(a + GAT_H))[lane];
    float d1 = e.x * a1.x + e.y * a1.y;
    float d2 = e.x * a2.x + e.y * a2.y;
    #pragma unroll
    for (int m = 32; m >= 1; m >>= 1) {
        d1 += __shfl_xor(d1, m, 64);
        d2 += __shfl_xor(d2, m, 64);
    }
    if (lane == 0) { t1[wid] = d1; t2[wid] = d2; }
}

// ---- kernel 2: main. One wave per CHUNK consecutive positions of one b. ----
// Restructured: ALL per-chunk scalar state (9 tokens + their t1/t2 dots) is
// prefetched with 3 vector loads (lane i -> token l0+i), then distributed via
// v_readlane (register-only). This removes the previous per-iteration
// vload(seq) -> vmcnt wait -> readfirstlane -> s_load(t1/t2) serial chain
// (3 chained memory latencies x 8 iterations, plus ~1.2M random scalar-cache
// misses). The 9 emb row loads now issue back-to-back after ONE wait.
__global__ __launch_bounds__(256) void k_main(const float* __restrict__ emb,
                                              const int* __restrict__ seq,
                                              const int* __restrict__ seq_l,
                                              const float* __restrict__ t1,
                                              const float* __restrict__ t2,
                                              const float* __restrict__ sbuf,
                                              float* __restrict__ out) {
    const int wid  = (blockIdx.x * blockDim.x + threadIdx.x) >> 6;
    const int lane = threadIdx.x & 63;
    const int b  = wid >> 6;                 // L/CHUNK = 64 chunks per sequence
    const int l0 = (wid & 63) * CHUNK;
    if (b >= GAT_B) return;

    const int sl = __builtin_amdgcn_readfirstlane(seq_l[b]);
    const float S1 = sbuf[0], S2 = sbuf[1];

    // Prefetch the chunk's 9 tokens and their dot-table entries.
    // Lane i (i<=8) handles token l0+i; lanes 9..63 duplicate lane 8 (same
    // cache line, free). Last chunk clamps index 512->511; that slot is only
    // consumed when need_next at k=7, which requires valid(l=511) == false
    // always (sl <= 511), so the clamped value is never used.
    int li = l0 + (lane < 9 ? lane : 8);
    if (li > GAT_L - 1) li = GAT_L - 1;
    const int   tokv = seq[b * GAT_L + li];
    const float t1v  = t1[tokv];
    const float t2v  = t2[tokv];

    const int tk0 = __builtin_amdgcn_readlane(tokv, 0);
    float2 R   = ((const float2*)(emb + (size_t)tk0 * GAT_H))[lane];
    float  t1c = readlane_f(t1v, 0);
    float  t2c = readlane_f(t2v, 0);
    float2* obase = (float2*)(out + ((size_t)b * GAT_L + l0) * GAT_H);

    #pragma unroll
    for (int k = 0; k < CHUNK; ++k) {
        const int l = l0 + k;
        const bool valid = (l < sl - 1);            // wave-uniform
        const bool need_next = valid || (k < CHUNK - 1);
        float2 Rn; float t1n = 0.f, t2n = 0.f;
        if (need_next) {
            const int tokn = __builtin_amdgcn_readlane(tokv, k + 1);  // SGPR
            Rn  = ((const float2*)(emb + (size_t)tokn * GAT_H))[lane];
            t1n = readlane_f(t1v, k + 1);
            t2n = readlane_f(t2v, k + 1);
        }
        v2f o2;
        if (valid) {
            const float pos  = (float)(sl - l);
            const float posn = pos - 1.0f;
            const float d1  = t1c + pos * S1;
            const float d2  = t2c + pos * S2;
            const float d2n = t2n + posn * S2;     // next position's self-a2 dot
            const float s0 = d1 + d2, s1 = d1 + d2n;
            const float mx = fmaxf(s0, s1);
            const float p0 = __expf(s0 - mx), p1 = __expf(s1 - mx);
            const float inv = 1.0f / (p0 + p1);
            const float att0 = p0 * inv, att1 = p1 * inv;
            o2.x = att0 * (R.x + pos) + att1 * (Rn.x + posn);
            o2.y = att0 * (R.y + pos) + att1 * (Rn.y + posn);
        } else {
            o2.x = R.x;                             // out = raw embedding
            o2.y = R.y;
        }
        __builtin_nontemporal_store(o2, (v2f*)(obase + (size_t)k * 64 + lane));
        if (need_next) { R = Rn; t1c = t1n; t2c = t2n; }
    }
}

extern "C" void kernel_launch(void* const* d_in, const int* in_sizes, int n_in,
                              void* d_out, int out_size, void* d_ws, size_t ws_size,
                              hipStream_t stream) {
    const float* emb   = (const float*)d_in[0];
    const float* a     = (const float*)d_in[1];
    const int*   seq   = (const int*)d_in[2];
    const int*   seq_l = (const int*)d_in[3];
    float* out = (float*)d_out;

    float* t1   = (float*)d_ws;             // V floats
    float* t2   = t1 + V_TOK;               // V floats
    float* sbuf = t2 + V_TOK;               // 2 floats

    k_sums<<<1, 64, 0, stream>>>(a, sbuf);

    {   // per-token dots: one wave per token
        const int waves = V_TOK;
        const int blocks = (waves * 64 + 255) / 256;
        k_tok<<<blocks, 256, 0, stream>>>(emb, a, t1, t2);
    }

    {   // main: B * (L/CHUNK) waves
        const int waves = GAT_B * (GAT_L / CHUNK);
        const int blocks = (waves * 64 + 255) / 256;
        k_main<<<blocks, 256, 0, stream>>>(emb, seq, seq_l, t1, t2, sbuf, out);
    }
}